// Round 4
// baseline (253.239 us; speedup 1.0000x reference)
//
#include <hip/hip_runtime.h>

// GradeWiseLinear: x (8,2048,128,16) f32, block-diagonal linear over last dim,
// grade dims {1,4,6,4,1}. Memory-bound: 128 MiB in + 128 MiB out, ~43 us floor.
//
// R6: R5 (persistent grid-stride + in-register quad transpose) with
//     NONTEMPORAL loads/stores (gfx950 `nt` bit).
//   Evidence ledger: R2/R3/R4/R5 — one-shot vs persistent, coalesced vs
//   strided, LDS-tiled vs shuffle, MLP 1..4 — ALL pinned at 75-84 us,
//   2.5-2.7 TB/s HBM, VALUBusy <=12%, 0 bank conflicts. Every structural
//   kernel-side lever is individually falsified. Remaining untested variable:
//   cache policy. The harness's 512 MiB poison fills stream WRITES at
//   6.7 TB/s through the same memory system; our kernels' cached accesses
//   allocate every streamed line in L2/L3 (counters: 64 MiB of reads L3-hit,
//   64 MiB HBM). NT loads/stores skip L2/L3 allocation (write-around stores,
//   non-allocating reads) -> no victim churn on 256 MiB of single-use data.
//   A/B: only the memory ops changed vs R5.
//
// Row handling (unchanged from R5, verified): lane-contiguous float4 loads
// put one 16-float row in each 4-lane quad (lane&3 = chunk j). Chunk j needs
// only chunks j^1, j^3: two shfl_xor per component. Compute is the verified
// branch-renamed R3 arithmetic. 4-way divergence costs ~70 FMA per 16 rows —
// irrelevant at VALUBusy ~12%.
//
// LDS weight layout (unchanged):
// [0] w0 | [1..16] w1 | [17..52] w2 | [53..68] w3 | [69] w4 | [70..85] biases

typedef float f4_t __attribute__((ext_vector_type(4)));

__global__ __launch_bounds__(256) void GradeWiseLinear_kernel(
    const float* __restrict__ x,
    const float* __restrict__ w0, const float* __restrict__ b0,
    const float* __restrict__ w1, const float* __restrict__ b1,
    const float* __restrict__ w2, const float* __restrict__ b2,
    const float* __restrict__ w3, const float* __restrict__ b3,
    const float* __restrict__ w4, const float* __restrict__ b4,
    float* __restrict__ out, int n4)
{
    __shared__ float s[86];
    {
        int t = threadIdx.x;
        if (t < 86) {
            float v;
            if      (t == 0)  v = w0[0];
            else if (t < 17)  v = w1[t - 1];
            else if (t < 53)  v = w2[t - 17];
            else if (t < 69)  v = w3[t - 53];
            else if (t == 69) v = w4[0];
            else if (t == 70) v = b0[0];
            else if (t < 75)  v = b1[t - 71];
            else if (t < 81)  v = b2[t - 75];
            else if (t < 85)  v = b3[t - 81];
            else              v = b4[0];
            s[t] = v;
        }
    }
    __syncthreads();

    const int stride = gridDim.x * 256;
    int g = blockIdx.x * 256 + threadIdx.x;
    if (g >= n4) return;

    const int j = g & 3;                      // constant across iterations
    const f4_t* __restrict__ x4 = (const f4_t*)x;
    f4_t* __restrict__ o4 = (f4_t*)out;

    f4_t cur = __builtin_nontemporal_load(x4 + g);
    for (;;) {
        // ---- prefetch next iteration (1-deep pipeline, no barrier gates) ----
        int gn = g + stride;
        bool have_next = (gn < n4);           // wave-uniform (n4 % 64 == 0)
        f4_t nxt;
        if (have_next) nxt = __builtin_nontemporal_load(x4 + gn);

        // ---- in-register quad transpose: neighbors at lane^1, lane^3 ----
        f4_t e1, e3;
        e1.x = __shfl_xor(cur.x, 1);
        e1.y = __shfl_xor(cur.y, 1);
        e1.z = __shfl_xor(cur.z, 1);
        e1.w = __shfl_xor(cur.w, 1);
        e3.x = __shfl_xor(cur.x, 3);
        e3.y = __shfl_xor(cur.y, 3);
        e3.z = __shfl_xor(cur.z, 3);
        e3.w = __shfl_xor(cur.w, 3);

        f4_t y;
        if (j == 0) {
            // a = cur, q = e1
            y.x = s[70] + s[0]  * cur.x;
            y.y = s[71] + s[1]  * cur.y + s[2]  * cur.z + s[3]  * cur.w + s[4]  * e1.x;
            y.z = s[72] + s[5]  * cur.y + s[6]  * cur.z + s[7]  * cur.w + s[8]  * e1.x;
            y.w = s[73] + s[9]  * cur.y + s[10] * cur.z + s[11] * cur.w + s[12] * e1.x;
        } else if (j == 1) {
            // a = e1, q = cur, c = e3
            y.x = s[74] + s[13] * e1.y  + s[14] * e1.z  + s[15] * e1.w  + s[16] * cur.x;
            y.y = s[75] + s[17] * cur.y + s[18] * cur.z + s[19] * cur.w
                        + s[20] * e3.x  + s[21] * e3.y  + s[22] * e3.z;
            y.z = s[76] + s[23] * cur.y + s[24] * cur.z + s[25] * cur.w
                        + s[26] * e3.x  + s[27] * e3.y  + s[28] * e3.z;
            y.w = s[77] + s[29] * cur.y + s[30] * cur.z + s[31] * cur.w
                        + s[32] * e3.x  + s[33] * e3.y  + s[34] * e3.z;
        } else if (j == 2) {
            // q = e3, c = cur, d = e1
            y.x = s[78] + s[35] * e3.y  + s[36] * e3.z  + s[37] * e3.w
                        + s[38] * cur.x + s[39] * cur.y + s[40] * cur.z;
            y.y = s[79] + s[41] * e3.y  + s[42] * e3.z  + s[43] * e3.w
                        + s[44] * cur.x + s[45] * cur.y + s[46] * cur.z;
            y.z = s[80] + s[47] * e3.y  + s[48] * e3.z  + s[49] * e3.w
                        + s[50] * cur.x + s[51] * cur.y + s[52] * cur.z;
            y.w = s[81] + s[53] * cur.w + s[54] * e1.x  + s[55] * e1.y  + s[56] * e1.z;
        } else {
            // c = e1, d = cur
            y.x = s[82] + s[57] * e1.w + s[58] * cur.x + s[59] * cur.y + s[60] * cur.z;
            y.y = s[83] + s[61] * e1.w + s[62] * cur.x + s[63] * cur.y + s[64] * cur.z;
            y.z = s[84] + s[65] * e1.w + s[66] * cur.x + s[67] * cur.y + s[68] * cur.z;
            y.w = s[85] + s[69] * cur.w;
        }

        __builtin_nontemporal_store(y, o4 + g);

        if (!have_next) break;
        cur = nxt;
        g = gn;
    }
}

extern "C" void kernel_launch(void* const* d_in, const int* in_sizes, int n_in,
                              void* d_out, int out_size, void* d_ws, size_t ws_size,
                              hipStream_t stream) {
    const float* x  = (const float*)d_in[0];
    const float* w0 = (const float*)d_in[1];
    const float* b0 = (const float*)d_in[2];
    const float* w1 = (const float*)d_in[3];
    const float* b1 = (const float*)d_in[4];
    const float* w2 = (const float*)d_in[5];
    const float* b2 = (const float*)d_in[6];
    const float* w3 = (const float*)d_in[7];
    const float* b3 = (const float*)d_in[8];
    const float* w4 = (const float*)d_in[9];
    const float* b4 = (const float*)d_in[10];
    float* out = (float*)d_out;

    int n4 = in_sizes[0] / 4;                // 8,388,608 float4 chunks
    int block = 256;
    int grid = (n4 + block - 1) / block;
    if (grid > 2048) grid = 2048;            // persistent: 8 blocks/CU, 16 iters

    GradeWiseLinear_kernel<<<grid, block, 0, stream>>>(
        x, w0, b0, w1, b1, w2, b2, w3, b3, w4, b4, out, n4);
}